// Round 6
// baseline (1324.857 us; speedup 1.0000x reference)
//
#include <hip/hip_runtime.h>
#include <cstddef>

// ---------------- conv1 v3: (32,3,152,152) -> relu 11x11 -> (32,32,142,142)
__global__ __launch_bounds__(256, 2) void conv1_v3(const float* __restrict__ x,
                                                   const float* __restrict__ w,
                                                   const float* __restrict__ bias,
                                                   float* __restrict__ out) {
  __shared__ __align__(16) float wsp[33 * 32 * 12];
  __shared__ __align__(16) float xs[3][26][44];
  const int wt = blockIdx.x, ht = blockIdx.y, b = blockIdx.z;
  const int tid = threadIdx.x;
  const int posg = tid & 31;
  const int ocg = tid >> 5;
  const int owg = posg & 1;
  const int ohl = posg >> 1;
  const int ih0 = ht * 16, iw0 = wt * 32;

  for (int j = tid; j < 11616; j += 256) {
    const int kw = j % 11, oc = (j / 11) % 32, r = j / 352;
    wsp[(r * 32 + oc) * 12 + kw] = w[oc * 363 + r * 11 + kw];
  }
  for (int j = tid; j < 3 * 26 * 42; j += 256) {
    const int ic = j / 1092, r = (j % 1092) / 42, c = j % 42;
    const int ih = min(ih0 + r, 151), iw = min(iw0 + c, 151);
    xs[ic][r][c] = x[((size_t)b * 3 + ic) * 23104 + ih * 152 + iw];
  }
  __syncthreads();

  const int oh = ih0 + ohl;
  if (oh >= 142) return;
  float acc[4][16] = {};
  for (int ic = 0; ic < 3; ++ic) {
    for (int kh = 0; kh < 11; ++kh) {
      const int r = ic * 11 + kh;
      float xv[28];
      const float* xr = &xs[ic][ohl + kh][owg * 16];
      #pragma unroll
      for (int j = 0; j < 7; ++j) *(float4*)&xv[4 * j] = *(const float4*)&xr[4 * j];
      float wv[4][12];
      #pragma unroll
      for (int o = 0; o < 4; ++o) {
        const float* wr = &wsp[(r * 32 + ocg * 4 + o) * 12];
        *(float4*)&wv[o][0] = *(const float4*)&wr[0];
        *(float4*)&wv[o][4] = *(const float4*)&wr[4];
        *(float4*)&wv[o][8] = *(const float4*)&wr[8];
      }
      #pragma unroll
      for (int kw = 0; kw < 11; ++kw)
        #pragma unroll
        for (int o = 0; o < 4; ++o)
          #pragma unroll
          for (int p = 0; p < 16; ++p)
            acc[o][p] += xv[kw + p] * wv[o][kw];
    }
  }

  const int ow0 = iw0 + owg * 16;
  #pragma unroll
  for (int o = 0; o < 4; ++o) {
    const int oc = ocg * 4 + o;
    const float bv = bias[oc];
    float* op = &out[(((size_t)b * 32 + oc) * 142 + oh) * 142 + ow0];
    if (ow0 + 16 <= 142) {
      #pragma unroll
      for (int p = 0; p < 16; p += 2) {
        float2 rv;
        rv.x = fmaxf(acc[o][p] + bv, 0.f);
        rv.y = fmaxf(acc[o][p + 1] + bv, 0.f);
        *(float2*)&op[p] = rv;
      }
    } else {
      for (int p = 0; p < 16; ++p)
        if (ow0 + p < 142) op[p] = fmaxf(acc[o][p] + bv, 0.f);
    }
  }
}

// ---------------- maxpool 3x3 s2 p1
__global__ __launch_bounds__(256) void pool_3_2_1(const float* __restrict__ in,
                                                  float* __restrict__ out) {
  const int idx = blockIdx.x * 256 + threadIdx.x;
  const int total = 32 * 32 * 71 * 71;
  if (idx >= total) return;
  const int ow = idx % 71;
  const int oh = (idx / 71) % 71;
  const int bc = idx / (71 * 71);
  const float* base = in + (size_t)bc * 142 * 142;
  float m = -1e30f;
  #pragma unroll
  for (int kh = 0; kh < 3; ++kh) {
    const int ih = oh * 2 - 1 + kh;
    if (ih < 0 || ih >= 142) continue;
    #pragma unroll
    for (int kw = 0; kw < 3; ++kw) {
      const int iw = ow * 2 - 1 + kw;
      if (iw < 0 || iw >= 142) continue;
      m = fmaxf(m, base[ih * 142 + iw]);
    }
  }
  out[idx] = m;
}

// ---------------- conv2: ic-split x4 partials + combine
__global__ __launch_bounds__(128, 2) void conv2_part(const float* __restrict__ x,
                                                     const float* __restrict__ w,
                                                     float* __restrict__ part) {
  __shared__ __align__(16) float wsp[2 * 9 * 16 * 12];
  __shared__ __align__(16) float xs[2][24][44];
  const int wt = blockIdx.x, ht = blockIdx.y;
  const int b = blockIdx.z >> 2, icg = blockIdx.z & 3;
  const int tid = threadIdx.x;
  const int posg = tid & 31;
  const int ocg = tid >> 5;
  const int owg = posg & 1, ohl = posg >> 1;
  const int ih0 = ht * 16, iw0 = wt * 32;
  float acc[4][16] = {};

  for (int ch = 0; ch < 4; ++ch) {
    __syncthreads();
    for (int j = tid; j < 2 * 9 * 16 * 9; j += 128) {
      const int kw = j % 9, oc = (j / 9) % 16, kh = (j / 144) % 9, icl = j / 1296;
      wsp[((icl * 9 + kh) * 16 + oc) * 12 + kw] =
          w[(size_t)oc * 2592 + (icg * 8 + ch * 2 + icl) * 81 + kh * 9 + kw];
    }
    for (int j = tid; j < 2 * 24 * 40; j += 128) {
      const int icl = j / 960, r = (j % 960) / 40, c = j % 40;
      const int ih = min(ih0 + r, 70), iw = min(iw0 + c, 70);
      xs[icl][r][c] =
          x[((size_t)b * 32 + icg * 8 + ch * 2 + icl) * 5041 + ih * 71 + iw];
    }
    __syncthreads();
    for (int icl = 0; icl < 2; ++icl) {
      for (int kh = 0; kh < 9; ++kh) {
        float xv[24];
        const float* xr = &xs[icl][ohl + kh][owg * 16];
        #pragma unroll
        for (int j = 0; j < 6; ++j) *(float4*)&xv[4 * j] = *(const float4*)&xr[4 * j];
        float wv[4][9];
        #pragma unroll
        for (int o = 0; o < 4; ++o) {
          const float* wr = &wsp[((icl * 9 + kh) * 16 + ocg * 4 + o) * 12];
          *(float4*)&wv[o][0] = *(const float4*)&wr[0];
          *(float4*)&wv[o][4] = *(const float4*)&wr[4];
          wv[o][8] = wr[8];
        }
        #pragma unroll
        for (int kw = 0; kw < 9; ++kw)
          #pragma unroll
          for (int o = 0; o < 4; ++o)
            #pragma unroll
            for (int p = 0; p < 16; ++p)
              acc[o][p] += xv[kw + p] * wv[o][kw];
      }
    }
  }

  const int oh = ih0 + ohl;
  if (oh >= 63) return;
  const int ow0 = iw0 + owg * 16;
  float* pp = part + (size_t)icg * 2032128;
  #pragma unroll
  for (int o = 0; o < 4; ++o) {
    const int oc = ocg * 4 + o;
    float* op = &pp[(((size_t)b * 16 + oc) * 63 + oh) * 63 + ow0];
    #pragma unroll
    for (int p = 0; p < 16; ++p)
      if (ow0 + p < 63) op[p] = acc[o][p];
  }
}

__global__ __launch_bounds__(256) void conv2_combine(const float* __restrict__ part,
                                                     const float* __restrict__ bias,
                                                     float* __restrict__ out) {
  const int i = blockIdx.x * 256 + threadIdx.x;
  if (i >= 2032128) return;
  const int oc = (i / 3969) & 15;
  const float v = part[i] + part[i + 2032128] + part[i + 2 * 2032128] +
                  part[i + 3 * 2032128] + bias[oc];
  out[i] = fmaxf(v, 0.f);
}

// ---------------- local conv v6: v5 structure + (a) ic-split x8 (2 ic/block)
// for 2x grid, (b) explicit double-buffered weight registers (named wfA/wfB,
// fully unrolled kc-pairs) so 8 w-loads stay in flight per wave.
// Block = 4 waves = 8 consecutive positions in one output row; shared x patch
// staged per-ic; thread = 4 oc x 4 b; weights streamed direct from global.
template <int KH, int S, int IH, int OH>
__global__ __launch_bounds__(256) void lc_v6(const float* __restrict__ x,
                                             const float* __restrict__ w,
                                             float* __restrict__ part) {
  constexpr int KHW = KH * KH;
  constexpr int NPOS = OH * OH;
  constexpr int NCH = 16 * KHW;
  constexpr int TILE = 8;
  constexpr int COLS = S * (TILE - 1) + KH;
  constexpr int TPR = (OH + TILE - 1) / TILE;
  constexpr int BSTR = 36;
  constexpr int KC4 = KHW / 4;                 // 20 / 12 / 6 (all even)
  __shared__ __align__(16) float xs[KH * COLS * BSTR];

  const int tile = blockIdx.x % TPR;
  const int oh = blockIdx.x / TPR;
  const int icg = blockIdx.y;                  // 0..7
  const int ow0 = min(tile * TILE, OH - TILE);
  const int tid = threadIdx.x;
  const int lane = tid & 63, wvi = tid >> 6;
  const int p = lane >> 5, t = lane & 31;
  const int og = t & 3, bg = t >> 2;
  const int ow_off = wvi * 2 + p;
  const int myow = ow0 + ow_off;
  const int pos = oh * OH + myow;
  const int in_row0 = oh * S, in_col0 = ow0 * S;
  const float* xb = &xs[(ow_off * S) * BSTR + bg * 4];

  float acc[4][4] = {};
  #pragma unroll
  for (int ics = 0; ics < 2; ++ics) {
    const int ic = icg * 2 + ics;
    __syncthreads();
    for (int j = tid; j < KH * COLS * 32; j += 256) {
      const int col = j % COLS;
      const int row = (j / COLS) % KH;
      const int b = j / (COLS * KH);
      xs[(row * COLS + col) * BSTR + b] =
          x[(((size_t)b * 16 + ic) * IH + in_row0 + row) * IH + in_col0 + col];
    }
    __syncthreads();

    const float* wic = w + ((size_t)pos * 16 + og * 4) * NCH + (size_t)ic * KHW;

    float wA[4][4], wB[4][4];
    #pragma unroll
    for (int o = 0; o < 4; ++o) {
      const float4 t4 = *(const float4*)&wic[o * NCH];
      wA[o][0] = t4.x; wA[o][1] = t4.y; wA[o][2] = t4.z; wA[o][3] = t4.w;
    }

    auto compute = [&](const float (&wf)[4][4], int kc) {
      #pragma unroll
      for (int kk = 0; kk < 4; ++kk) {
        const int k = kc * 4 + kk;
        const int kh = k / KH, kw = k - kh * KH;
        const float4 xv = *(const float4*)&xb[(kh * COLS + kw) * BSTR];
        #pragma unroll
        for (int o = 0; o < 4; ++o) {
          acc[o][0] += wf[o][kk] * xv.x;
          acc[o][1] += wf[o][kk] * xv.y;
          acc[o][2] += wf[o][kk] * xv.z;
          acc[o][3] += wf[o][kk] * xv.w;
        }
      }
    };

    #pragma unroll
    for (int kc2 = 0; kc2 < KC4 / 2; ++kc2) {
      const int kcA = 2 * kc2, kcB = 2 * kc2 + 1;
      #pragma unroll
      for (int o = 0; o < 4; ++o) {
        const float4 t4 = *(const float4*)&wic[o * NCH + kcB * 4];
        wB[o][0] = t4.x; wB[o][1] = t4.y; wB[o][2] = t4.z; wB[o][3] = t4.w;
      }
      compute(wA, kcA);
      const int kcN = (kcB + 1 < KC4) ? kcB + 1 : kcB;   // folds at compile time
      #pragma unroll
      for (int o = 0; o < 4; ++o) {
        const float4 t4 = *(const float4*)&wic[o * NCH + kcN * 4];
        wA[o][0] = t4.x; wA[o][1] = t4.y; wA[o][2] = t4.z; wA[o][3] = t4.w;
      }
      compute(wB, kcB);
    }
    {  // tail k = KHW-1 (KHW % 4 == 1)
      const int k = KHW - 1;
      const int kh = k / KH, kw = k - kh * KH;
      const float4 xv = *(const float4*)&xb[(kh * COLS + kw) * BSTR];
      #pragma unroll
      for (int o = 0; o < 4; ++o) {
        const float wt2 = wic[o * NCH + k];
        acc[o][0] += wt2 * xv.x;
        acc[o][1] += wt2 * xv.y;
        acc[o][2] += wt2 * xv.z;
        acc[o][3] += wt2 * xv.w;
      }
    }
  }

  float* pp = part + (size_t)icg * (32 * 16 * NPOS);
  #pragma unroll
  for (int o = 0; o < 4; ++o) {
    const int oc = og * 4 + o;
    #pragma unroll
    for (int i = 0; i < 4; ++i) {
      const int b = bg * 4 + i;
      pp[(((size_t)b * 16 + oc) * OH + oh) * OH + myow] = acc[o][i];
    }
  }
}

// combine 8 ic-partials + bias + relu. total = 32*16*npos.
__global__ __launch_bounds__(256) void lc_combine8(const float* __restrict__ part,
                                                   const float* __restrict__ bias,
                                                   float* __restrict__ out,
                                                   int npos, int total) {
  const int i = blockIdx.x * 256 + threadIdx.x;
  if (i >= total) return;
  const int pos = i % npos;
  const int oc = (i / npos) & 15;
  float v = bias[oc * npos + pos];
  #pragma unroll
  for (int j = 0; j < 8; ++j) v += part[i + (size_t)j * total];
  out[i] = fmaxf(v, 0.f);
}

// ---------------- fc1: transpose + reg-tiled GEMM
__global__ __launch_bounds__(256) void transpose_x(const float* __restrict__ h,
                                                   float* __restrict__ xt) {
  __shared__ float t[32][33];
  const int k0 = blockIdx.x * 32;
  const int lk = threadIdx.x & 31, lb = threadIdx.x >> 5;
  for (int bb = lb; bb < 32; bb += 8) {
    const int k = k0 + lk;
    t[bb][lk] = (k < 7056) ? h[(size_t)bb * 7056 + k] : 0.f;
  }
  __syncthreads();
  for (int kk = lb; kk < 32; kk += 8) {
    const int k = k0 + kk;
    if (k < 7056) xt[(size_t)k * 32 + lk] = t[lk][kk];
  }
}

__global__ __launch_bounds__(256) void fc1_v2(const float* __restrict__ xt,
                                              const float* __restrict__ w,
                                              const float* __restrict__ bias,
                                              float* __restrict__ out) {
  const int lane = threadIdx.x & 63;
  const int b0 = (threadIdx.x >> 6) * 8;
  const int n0 = blockIdx.x * 8;
  float acc[8][8] = {};
  for (int it = 0; it < 28; ++it) {
    const int kb = it * 256 + lane * 4;
    float4 wf[8], xa[4], xb[4];
    if (kb < 7056) {
      #pragma unroll
      for (int n = 0; n < 8; ++n)
        wf[n] = *(const float4*)&w[(size_t)(n0 + n) * 7056 + kb];
      #pragma unroll
      for (int j = 0; j < 4; ++j) {
        xa[j] = *(const float4*)&xt[(size_t)(kb + j) * 32 + b0];
        xb[j] = *(const float4*)&xt[(size_t)(kb + j) * 32 + b0 + 4];
      }
    } else {
      #pragma unroll
      for (int n = 0; n < 8; ++n) wf[n] = make_float4(0.f, 0.f, 0.f, 0.f);
      #pragma unroll
      for (int j = 0; j < 4; ++j) {
        xa[j] = make_float4(0.f, 0.f, 0.f, 0.f);
        xb[j] = make_float4(0.f, 0.f, 0.f, 0.f);
      }
    }
    #pragma unroll
    for (int n = 0; n < 8; ++n) {
      const float wk[4] = {wf[n].x, wf[n].y, wf[n].z, wf[n].w};
      #pragma unroll
      for (int j = 0; j < 4; ++j) {
        acc[n][0] += wk[j] * xa[j].x;
        acc[n][1] += wk[j] * xa[j].y;
        acc[n][2] += wk[j] * xa[j].z;
        acc[n][3] += wk[j] * xa[j].w;
        acc[n][4] += wk[j] * xb[j].x;
        acc[n][5] += wk[j] * xb[j].y;
        acc[n][6] += wk[j] * xb[j].z;
        acc[n][7] += wk[j] * xb[j].w;
      }
    }
  }
  #pragma unroll
  for (int n = 0; n < 8; ++n)
    #pragma unroll
    for (int c = 0; c < 8; ++c)
      #pragma unroll
      for (int m = 1; m < 64; m <<= 1)
        acc[n][c] += __shfl_xor(acc[n][c], m, 64);
  float val = 0.f;
  #pragma unroll
  for (int n = 0; n < 8; ++n)
    #pragma unroll
    for (int c = 0; c < 8; ++c)
      if (lane == n * 8 + c) val = acc[n][c];
  const int n_l = lane >> 3, b_l = lane & 7;
  out[(size_t)(b0 + b_l) * 4096 + n0 + n_l] = val + bias[n0 + n_l];
}

extern "C" void kernel_launch(void* const* d_in, const int* in_sizes, int n_in,
                              void* d_out, int out_size, void* d_ws, size_t ws_size,
                              hipStream_t stream) {
  const float* x       = (const float*)d_in[0];
  const float* conv1_w = (const float*)d_in[1];
  const float* conv1_b = (const float*)d_in[2];
  const float* conv2_w = (const float*)d_in[3];
  const float* conv2_b = (const float*)d_in[4];
  const float* lc1_w   = (const float*)d_in[5];
  const float* lc1_b   = (const float*)d_in[6];
  const float* lc2_w   = (const float*)d_in[7];
  const float* lc2_b   = (const float*)d_in[8];
  const float* lc3_w   = (const float*)d_in[9];
  const float* lc3_b   = (const float*)d_in[10];
  const float* fc1_w   = (const float*)d_in[11];
  const float* fc1_b   = (const float*)d_in[12];
  float* out = (float*)d_out;
  char* ws = (char*)d_ws;

  float* h1  = (float*)(ws + 0);           // 32*32*142*142      82,591,744 B
  float* p1  = (float*)(ws + 82591744);    // 32*32*71*71        20,647,936 B
  float* h2  = (float*)(ws + 103239680);   // 32*16*63*63         8,128,512 B
  float* h3  = (float*)(ws + 0);           // 32*16*55*55         6,195,200 B
  float* h4  = (float*)(ws + 8388608);     // 32*16*25*25         1,280,000 B
  float* h5  = (float*)(ws + 16777216);    // 32*16*21*21           903,168 B
  float* xt  = (float*)(ws + 33554432);    // 7056*32               903,168 B
  float* c2p = (float*)(ws + 41943040);    // 4*32*16*63*63      32,514,048 B (dead after conv2_combine)
  float* lcp = (float*)(ws + 41943040);    // 8*32*16*55*55 max  49,561,600 B (reused per lc layer)

  conv1_v3<<<dim3(5, 9, 32), 256, 0, stream>>>(x, conv1_w, conv1_b, h1);
  pool_3_2_1<<<20164, 256, 0, stream>>>(h1, p1);
  conv2_part<<<dim3(2, 4, 128), 128, 0, stream>>>(p1, conv2_w, c2p);
  conv2_combine<<<7938, 256, 0, stream>>>(c2p, conv2_b, h2);

  lc_v6<9, 1, 63, 55><<<dim3(7 * 55, 8), 256, 0, stream>>>(h2, lc1_w, lcp);
  lc_combine8<<<(32 * 16 * 3025 + 255) / 256, 256, 0, stream>>>(
      lcp, lc1_b, h3, 3025, 32 * 16 * 3025);
  lc_v6<7, 2, 55, 25><<<dim3(4 * 25, 8), 256, 0, stream>>>(h3, lc2_w, lcp);
  lc_combine8<<<(32 * 16 * 625 + 255) / 256, 256, 0, stream>>>(
      lcp, lc2_b, h4, 625, 32 * 16 * 625);
  lc_v6<5, 1, 25, 21><<<dim3(3 * 21, 8), 256, 0, stream>>>(h4, lc3_w, lcp);
  lc_combine8<<<(32 * 16 * 441 + 255) / 256, 256, 0, stream>>>(
      lcp, lc3_b, h5, 441, 32 * 16 * 441);

  transpose_x<<<221, 256, 0, stream>>>(h5, xt);
  fc1_v2<<<512, 256, 0, stream>>>(xt, fc1_w, fc1_b, out);
}

// Round 7
// 873.951 us; speedup vs baseline: 1.5159x; 1.5159x over previous
//
#include <hip/hip_runtime.h>
#include <cstddef>

// ---------------- conv1 v3: (32,3,152,152) -> relu 11x11 -> (32,32,142,142)
__global__ __launch_bounds__(256, 2) void conv1_v3(const float* __restrict__ x,
                                                   const float* __restrict__ w,
                                                   const float* __restrict__ bias,
                                                   float* __restrict__ out) {
  __shared__ __align__(16) float wsp[33 * 32 * 12];
  __shared__ __align__(16) float xs[3][26][44];
  const int wt = blockIdx.x, ht = blockIdx.y, b = blockIdx.z;
  const int tid = threadIdx.x;
  const int posg = tid & 31;
  const int ocg = tid >> 5;
  const int owg = posg & 1;
  const int ohl = posg >> 1;
  const int ih0 = ht * 16, iw0 = wt * 32;

  for (int j = tid; j < 11616; j += 256) {
    const int kw = j % 11, oc = (j / 11) % 32, r = j / 352;
    wsp[(r * 32 + oc) * 12 + kw] = w[oc * 363 + r * 11 + kw];
  }
  for (int j = tid; j < 3 * 26 * 42; j += 256) {
    const int ic = j / 1092, r = (j % 1092) / 42, c = j % 42;
    const int ih = min(ih0 + r, 151), iw = min(iw0 + c, 151);
    xs[ic][r][c] = x[((size_t)b * 3 + ic) * 23104 + ih * 152 + iw];
  }
  __syncthreads();

  const int oh = ih0 + ohl;
  if (oh >= 142) return;
  float acc[4][16] = {};
  for (int ic = 0; ic < 3; ++ic) {
    for (int kh = 0; kh < 11; ++kh) {
      const int r = ic * 11 + kh;
      float xv[28];
      const float* xr = &xs[ic][ohl + kh][owg * 16];
      #pragma unroll
      for (int j = 0; j < 7; ++j) *(float4*)&xv[4 * j] = *(const float4*)&xr[4 * j];
      float wv[4][12];
      #pragma unroll
      for (int o = 0; o < 4; ++o) {
        const float* wr = &wsp[(r * 32 + ocg * 4 + o) * 12];
        *(float4*)&wv[o][0] = *(const float4*)&wr[0];
        *(float4*)&wv[o][4] = *(const float4*)&wr[4];
        *(float4*)&wv[o][8] = *(const float4*)&wr[8];
      }
      #pragma unroll
      for (int kw = 0; kw < 11; ++kw)
        #pragma unroll
        for (int o = 0; o < 4; ++o)
          #pragma unroll
          for (int p = 0; p < 16; ++p)
            acc[o][p] += xv[kw + p] * wv[o][kw];
    }
  }

  const int ow0 = iw0 + owg * 16;
  #pragma unroll
  for (int o = 0; o < 4; ++o) {
    const int oc = ocg * 4 + o;
    const float bv = bias[oc];
    float* op = &out[(((size_t)b * 32 + oc) * 142 + oh) * 142 + ow0];
    if (ow0 + 16 <= 142) {
      #pragma unroll
      for (int p = 0; p < 16; p += 2) {
        float2 rv;
        rv.x = fmaxf(acc[o][p] + bv, 0.f);
        rv.y = fmaxf(acc[o][p + 1] + bv, 0.f);
        *(float2*)&op[p] = rv;
      }
    } else {
      for (int p = 0; p < 16; ++p)
        if (ow0 + p < 142) op[p] = fmaxf(acc[o][p] + bv, 0.f);
    }
  }
}

// ---------------- maxpool 3x3 s2 p1
__global__ __launch_bounds__(256) void pool_3_2_1(const float* __restrict__ in,
                                                  float* __restrict__ out) {
  const int idx = blockIdx.x * 256 + threadIdx.x;
  const int total = 32 * 32 * 71 * 71;
  if (idx >= total) return;
  const int ow = idx % 71;
  const int oh = (idx / 71) % 71;
  const int bc = idx / (71 * 71);
  const float* base = in + (size_t)bc * 142 * 142;
  float m = -1e30f;
  #pragma unroll
  for (int kh = 0; kh < 3; ++kh) {
    const int ih = oh * 2 - 1 + kh;
    if (ih < 0 || ih >= 142) continue;
    #pragma unroll
    for (int kw = 0; kw < 3; ++kw) {
      const int iw = ow * 2 - 1 + kw;
      if (iw < 0 || iw >= 142) continue;
      m = fmaxf(m, base[ih * 142 + iw]);
    }
  }
  out[idx] = m;
}

// ---------------- conv2: ic-split x4 partials + combine
__global__ __launch_bounds__(128, 2) void conv2_part(const float* __restrict__ x,
                                                     const float* __restrict__ w,
                                                     float* __restrict__ part) {
  __shared__ __align__(16) float wsp[2 * 9 * 16 * 12];
  __shared__ __align__(16) float xs[2][24][44];
  const int wt = blockIdx.x, ht = blockIdx.y;
  const int b = blockIdx.z >> 2, icg = blockIdx.z & 3;
  const int tid = threadIdx.x;
  const int posg = tid & 31;
  const int ocg = tid >> 5;
  const int owg = posg & 1, ohl = posg >> 1;
  const int ih0 = ht * 16, iw0 = wt * 32;
  float acc[4][16] = {};

  for (int ch = 0; ch < 4; ++ch) {
    __syncthreads();
    for (int j = tid; j < 2 * 9 * 16 * 9; j += 128) {
      const int kw = j % 9, oc = (j / 9) % 16, kh = (j / 144) % 9, icl = j / 1296;
      wsp[((icl * 9 + kh) * 16 + oc) * 12 + kw] =
          w[(size_t)oc * 2592 + (icg * 8 + ch * 2 + icl) * 81 + kh * 9 + kw];
    }
    for (int j = tid; j < 2 * 24 * 40; j += 128) {
      const int icl = j / 960, r = (j % 960) / 40, c = j % 40;
      const int ih = min(ih0 + r, 70), iw = min(iw0 + c, 70);
      xs[icl][r][c] =
          x[((size_t)b * 32 + icg * 8 + ch * 2 + icl) * 5041 + ih * 71 + iw];
    }
    __syncthreads();
    for (int icl = 0; icl < 2; ++icl) {
      for (int kh = 0; kh < 9; ++kh) {
        float xv[24];
        const float* xr = &xs[icl][ohl + kh][owg * 16];
        #pragma unroll
        for (int j = 0; j < 6; ++j) *(float4*)&xv[4 * j] = *(const float4*)&xr[4 * j];
        float wv[4][9];
        #pragma unroll
        for (int o = 0; o < 4; ++o) {
          const float* wr = &wsp[((icl * 9 + kh) * 16 + ocg * 4 + o) * 12];
          *(float4*)&wv[o][0] = *(const float4*)&wr[0];
          *(float4*)&wv[o][4] = *(const float4*)&wr[4];
          wv[o][8] = wr[8];
        }
        #pragma unroll
        for (int kw = 0; kw < 9; ++kw)
          #pragma unroll
          for (int o = 0; o < 4; ++o)
            #pragma unroll
            for (int p = 0; p < 16; ++p)
              acc[o][p] += xv[kw + p] * wv[o][kw];
      }
    }
  }

  const int oh = ih0 + ohl;
  if (oh >= 63) return;
  const int ow0 = iw0 + owg * 16;
  float* pp = part + (size_t)icg * 2032128;
  #pragma unroll
  for (int o = 0; o < 4; ++o) {
    const int oc = ocg * 4 + o;
    float* op = &pp[(((size_t)b * 16 + oc) * 63 + oh) * 63 + ow0];
    #pragma unroll
    for (int p = 0; p < 16; ++p)
      if (ow0 + p < 63) op[p] = acc[o][p];
  }
}

__global__ __launch_bounds__(256) void conv2_combine(const float* __restrict__ part,
                                                     const float* __restrict__ bias,
                                                     float* __restrict__ out) {
  const int i = blockIdx.x * 256 + threadIdx.x;
  if (i >= 2032128) return;
  const int oc = (i / 3969) & 15;
  const float v = part[i] + part[i + 2032128] + part[i + 2 * 2032128] +
                  part[i + 3 * 2032128] + bias[oc];
  out[i] = fmaxf(v, 0.f);
}

// ---------------- local conv v7: wave = 4 pos x (2 og x 8 bg); thread = 8oc x 4b.
// Block = 4 waves = 16-position row tile; x staged per-ic in LDS [row][col][b36];
// ic-split x8 (2 ic per block) into f32 partials. Weights streamed direct from
// global: 8 float4 per kc per lane (1024 B in flight per wave), no LDS for w.
// unroll 1 on ic/kc loops + launch_bounds cap to avoid v6's VGPR blowup.
template <int KH, int S, int IH, int OH>
__global__ __launch_bounds__(256, 4) void lc_v7(const float* __restrict__ x,
                                                const float* __restrict__ w,
                                                float* __restrict__ part) {
  constexpr int KHW = KH * KH;
  constexpr int NPOS = OH * OH;
  constexpr int WOC = 16 * KHW;              // per-oc stride (ic-major inside)
  constexpr int TILE = 16;
  constexpr int COLS = S * (TILE - 1) + KH;
  constexpr int TPR = (OH + TILE - 1) / TILE;
  constexpr int BSTR = 36;
  constexpr int KC4 = KHW / 4;               // 20 / 12 / 6
  __shared__ __align__(16) float xs[KH * COLS * BSTR];

  const int tile = blockIdx.x % TPR;
  const int oh = blockIdx.x / TPR;
  const int icg = blockIdx.y;                // 0..7
  const int ow0 = min(tile * TILE, OH - TILE);
  const int tid = threadIdx.x;
  const int lane = tid & 63, wvi = tid >> 6;
  const int p = lane >> 4;                   // 0..3 (position within wave)
  const int og = (lane >> 3) & 1;            // 0..1 -> oc0 = og*8
  const int bg = lane & 7;                   // b0 = bg*4
  const int ow_off = wvi * 4 + p;            // 0..15
  const int myow = ow0 + ow_off;
  const int pos = oh * OH + myow;
  const int in_row0 = oh * S, in_col0 = ow0 * S;

  float acc[8][4] = {};
  #pragma unroll 1
  for (int ics = 0; ics < 2; ++ics) {
    const int ic = icg * 2 + ics;
    __syncthreads();
    for (int j = tid; j < KH * COLS * 32; j += 256) {
      const int col = j % COLS;
      const int row = (j / COLS) % KH;
      const int b = j / (COLS * KH);
      xs[(row * COLS + col) * BSTR + b] =
          x[(((size_t)b * 16 + ic) * IH + in_row0 + row) * IH + in_col0 + col];
    }
    __syncthreads();

    const float* wic = w + ((size_t)pos * 16 + og * 8) * WOC + (size_t)ic * KHW;
    const float* xbase = &xs[(ow_off * S) * BSTR + bg * 4];

    #pragma unroll 1
    for (int kc = 0; kc < KC4; ++kc) {
      float4 wf[8];
      #pragma unroll
      for (int o = 0; o < 8; ++o)
        wf[o] = *(const float4*)&wic[o * WOC + kc * 4];
      float4 xv[4];
      #pragma unroll
      for (int kk = 0; kk < 4; ++kk) {
        const int k = kc * 4 + kk;
        const int kh = k / KH, kw = k - kh * KH;
        xv[kk] = *(const float4*)&xbase[(kh * COLS + kw) * BSTR];
      }
      #pragma unroll
      for (int kk = 0; kk < 4; ++kk) {
        const float4 xk = xv[kk];
        #pragma unroll
        for (int o = 0; o < 8; ++o) {
          const float wv = (kk == 0) ? wf[o].x
                         : (kk == 1) ? wf[o].y
                         : (kk == 2) ? wf[o].z
                                     : wf[o].w;
          acc[o][0] += wv * xk.x;
          acc[o][1] += wv * xk.y;
          acc[o][2] += wv * xk.z;
          acc[o][3] += wv * xk.w;
        }
      }
    }
    {  // tail k = KHW-1 (KHW % 4 == 1 for 81/49/25)
      const int k = KHW - 1;
      const float4 xk = *(const float4*)&xbase[((KH - 1) * COLS + KH - 1) * BSTR];
      #pragma unroll
      for (int o = 0; o < 8; ++o) {
        const float wv = wic[o * WOC + k];
        acc[o][0] += wv * xk.x;
        acc[o][1] += wv * xk.y;
        acc[o][2] += wv * xk.z;
        acc[o][3] += wv * xk.w;
      }
    }
  }

  float* pp = part + (size_t)icg * (32 * 16 * NPOS);
  #pragma unroll
  for (int o = 0; o < 8; ++o) {
    const int oc = og * 8 + o;
    #pragma unroll
    for (int i = 0; i < 4; ++i) {
      const int b = bg * 4 + i;
      pp[(((size_t)b * 16 + oc) * OH + oh) * OH + myow] = acc[o][i];
    }
  }
}

// combine 8 ic-partials + bias + relu. total = 32*16*npos.
__global__ __launch_bounds__(256) void lc_combine8(const float* __restrict__ part,
                                                   const float* __restrict__ bias,
                                                   float* __restrict__ out,
                                                   int npos, int total) {
  const int i = blockIdx.x * 256 + threadIdx.x;
  if (i >= total) return;
  const int pos = i % npos;
  const int oc = (i / npos) & 15;
  float v = bias[oc * npos + pos];
  #pragma unroll
  for (int j = 0; j < 8; ++j) v += part[i + (size_t)j * total];
  out[i] = fmaxf(v, 0.f);
}

// ---------------- fc1: transpose + reg-tiled GEMM
__global__ __launch_bounds__(256) void transpose_x(const float* __restrict__ h,
                                                   float* __restrict__ xt) {
  __shared__ float t[32][33];
  const int k0 = blockIdx.x * 32;
  const int lk = threadIdx.x & 31, lb = threadIdx.x >> 5;
  for (int bb = lb; bb < 32; bb += 8) {
    const int k = k0 + lk;
    t[bb][lk] = (k < 7056) ? h[(size_t)bb * 7056 + k] : 0.f;
  }
  __syncthreads();
  for (int kk = lb; kk < 32; kk += 8) {
    const int k = k0 + kk;
    if (k < 7056) xt[(size_t)k * 32 + lk] = t[lk][kk];
  }
}

__global__ __launch_bounds__(256) void fc1_v2(const float* __restrict__ xt,
                                              const float* __restrict__ w,
                                              const float* __restrict__ bias,
                                              float* __restrict__ out) {
  const int lane = threadIdx.x & 63;
  const int b0 = (threadIdx.x >> 6) * 8;
  const int n0 = blockIdx.x * 8;
  float acc[8][8] = {};
  for (int it = 0; it < 28; ++it) {
    const int kb = it * 256 + lane * 4;
    float4 wf[8], xa[4], xb[4];
    if (kb < 7056) {
      #pragma unroll
      for (int n = 0; n < 8; ++n)
        wf[n] = *(const float4*)&w[(size_t)(n0 + n) * 7056 + kb];
      #pragma unroll
      for (int j = 0; j < 4; ++j) {
        xa[j] = *(const float4*)&xt[(size_t)(kb + j) * 32 + b0];
        xb[j] = *(const float4*)&xt[(size_t)(kb + j) * 32 + b0 + 4];
      }
    } else {
      #pragma unroll
      for (int n = 0; n < 8; ++n) wf[n] = make_float4(0.f, 0.f, 0.f, 0.f);
      #pragma unroll
      for (int j = 0; j < 4; ++j) {
        xa[j] = make_float4(0.f, 0.f, 0.f, 0.f);
        xb[j] = make_float4(0.f, 0.f, 0.f, 0.f);
      }
    }
    #pragma unroll
    for (int n = 0; n < 8; ++n) {
      const float wk[4] = {wf[n].x, wf[n].y, wf[n].z, wf[n].w};
      #pragma unroll
      for (int j = 0; j < 4; ++j) {
        acc[n][0] += wk[j] * xa[j].x;
        acc[n][1] += wk[j] * xa[j].y;
        acc[n][2] += wk[j] * xa[j].z;
        acc[n][3] += wk[j] * xa[j].w;
        acc[n][4] += wk[j] * xb[j].x;
        acc[n][5] += wk[j] * xb[j].y;
        acc[n][6] += wk[j] * xb[j].z;
        acc[n][7] += wk[j] * xb[j].w;
      }
    }
  }
  #pragma unroll
  for (int n = 0; n < 8; ++n)
    #pragma unroll
    for (int c = 0; c < 8; ++c)
      #pragma unroll
      for (int m = 1; m < 64; m <<= 1)
        acc[n][c] += __shfl_xor(acc[n][c], m, 64);
  float val = 0.f;
  #pragma unroll
  for (int n = 0; n < 8; ++n)
    #pragma unroll
    for (int c = 0; c < 8; ++c)
      if (lane == n * 8 + c) val = acc[n][c];
  const int n_l = lane >> 3, b_l = lane & 7;
  out[(size_t)(b0 + b_l) * 4096 + n0 + n_l] = val + bias[n0 + n_l];
}

extern "C" void kernel_launch(void* const* d_in, const int* in_sizes, int n_in,
                              void* d_out, int out_size, void* d_ws, size_t ws_size,
                              hipStream_t stream) {
  const float* x       = (const float*)d_in[0];
  const float* conv1_w = (const float*)d_in[1];
  const float* conv1_b = (const float*)d_in[2];
  const float* conv2_w = (const float*)d_in[3];
  const float* conv2_b = (const float*)d_in[4];
  const float* lc1_w   = (const float*)d_in[5];
  const float* lc1_b   = (const float*)d_in[6];
  const float* lc2_w   = (const float*)d_in[7];
  const float* lc2_b   = (const float*)d_in[8];
  const float* lc3_w   = (const float*)d_in[9];
  const float* lc3_b   = (const float*)d_in[10];
  const float* fc1_w   = (const float*)d_in[11];
  const float* fc1_b   = (const float*)d_in[12];
  float* out = (float*)d_out;
  char* ws = (char*)d_ws;

  float* h1  = (float*)(ws + 0);           // 32*32*142*142      82,591,744 B
  float* p1  = (float*)(ws + 82591744);    // 32*32*71*71        20,647,936 B
  float* h2  = (float*)(ws + 103239680);   // 32*16*63*63         8,128,512 B
  float* h3  = (float*)(ws + 0);           // 32*16*55*55         6,195,200 B
  float* h4  = (float*)(ws + 8388608);     // 32*16*25*25         1,280,000 B
  float* h5  = (float*)(ws + 16777216);    // 32*16*21*21           903,168 B
  float* xt  = (float*)(ws + 33554432);    // 7056*32               903,168 B
  float* c2p = (float*)(ws + 41943040);    // 4*32*16*63*63      32,514,048 B (dead after conv2_combine)
  float* lcp = (float*)(ws + 41943040);    // 8*32*16*55*55 max  49,561,600 B (reused per lc layer)

  conv1_v3<<<dim3(5, 9, 32), 256, 0, stream>>>(x, conv1_w, conv1_b, h1);
  pool_3_2_1<<<20164, 256, 0, stream>>>(h1, p1);
  conv2_part<<<dim3(2, 4, 128), 128, 0, stream>>>(p1, conv2_w, c2p);
  conv2_combine<<<7938, 256, 0, stream>>>(c2p, conv2_b, h2);

  lc_v7<9, 1, 63, 55><<<dim3(4 * 55, 8), 256, 0, stream>>>(h2, lc1_w, lcp);
  lc_combine8<<<(32 * 16 * 3025 + 255) / 256, 256, 0, stream>>>(
      lcp, lc1_b, h3, 3025, 32 * 16 * 3025);
  lc_v7<7, 2, 55, 25><<<dim3(2 * 25, 8), 256, 0, stream>>>(h3, lc2_w, lcp);
  lc_combine8<<<(32 * 16 * 625 + 255) / 256, 256, 0, stream>>>(
      lcp, lc2_b, h4, 625, 32 * 16 * 625);
  lc_v7<5, 1, 25, 21><<<dim3(2 * 21, 8), 256, 0, stream>>>(h4, lc3_w, lcp);
  lc_combine8<<<(32 * 16 * 441 + 255) / 256, 256, 0, stream>>>(
      lcp, lc3_b, h5, 441, 32 * 16 * 441);

  transpose_x<<<221, 256, 0, stream>>>(h5, xt);
  fc1_v2<<<512, 256, 0, stream>>>(xt, fc1_w, fc1_b, out);
}